// Round 4
// baseline (251.929 us; speedup 1.0000x reference)
//
#include <hip/hip_runtime.h>

// Overlap-add, gather formulation. Wave-LOCAL ILP=4: each block owns 4
// ADJACENT 256-group chunks (16KB contiguous output window); thread i handles
// groups base + k*256 + i, k=0..3. Per-instruction coalescing identical to
// round 0 (64 lanes <-> 64 consecutive float4 = full 1KB lines), but 8
// independent loads in flight per thread.
//
// Geometry fixed by setup_inputs(): B=32, NF=4000, FS=320, shift=160.
// sig_length = (NF-1)*shift + FS = 640160.
// Output sample t is covered by frames f with t - f*shift in [0, FS):
//   f = q = t/shift (offset r = t%shift)   if q <= NF-1
//   f = q-1         (offset r + shift)     if q >= 1
// Overlap count = 2 interior, 1 for t < shift and t >= NF*shift.
//
// Measured history (total = ~174us harness fills/gaps + kernel):
//  r0 plain 1-float4/thread:            kernel ~73us (total 247.2)  <- best
//  r1 consecutive-64B-per-thread:       kernel 105us (partial-line stores,
//     1.55x write amplification) -- lane MUST own consecutive float4 group
//  r2 ILP4, pieces 5MB apart:           kernel ~78us (locality loss)
//  r3 r0 + nontemporal store:           kernel ~74us (NT = neutral)
//  VALUBusy 1.4-5%, occupancy ~68%, 20 VGPR: not VALU/occupancy-bound.
//  Kernel BW ~2.2 TB/s of 6.3 -> latency/issue-bound is the last theory.

constexpr int B       = 32;
constexpr int NF      = 4000;
constexpr int FS      = 320;
constexpr int SHIFT   = 160;
constexpr int SIG_LEN = (NF - 1) * SHIFT + FS;   // 640160
constexpr int GROUPS_PER_B = SIG_LEN / 4;        // 160040 float4 groups per batch
constexpr int TOTAL_G = B * GROUPS_PER_B;        // 5,121,280 float4 groups
constexpr int QDIV    = SHIFT / 4;               // 40 groups per shift
constexpr int BLOCK   = 256;
constexpr int NCHUNK  = TOTAL_G / BLOCK;         // 20005 chunks of 256 groups
constexpr int U       = 4;                       // adjacent chunks per block
constexpr int NBLOCKS = (NCHUNK + U - 1) / U;    // 5002

typedef float f32x4 __attribute__((ext_vector_type(4)));

__global__ __launch_bounds__(BLOCK)
void ola_gather_wu4(const float* __restrict__ in, float* __restrict__ out) {
    const int tid = threadIdx.x;
    const int c0  = blockIdx.x * U;

    f32x4 va[U], vb[U];
    int   bv[U], remv[U], qv[U];
    bool  valid[U];

    // Phase 1: issue all loads (up to 8 independent global_load_dwordx4).
    #pragma unroll
    for (int k = 0; k < U; ++k) {
        const int c = c0 + k;
        valid[k] = (c < NCHUNK);
        const int g   = valid[k] ? (c * BLOCK + tid) : 0;
        const int b   = g / GROUPS_PER_B;            // batch (magic-mul)
        const int rem = g - b * GROUPS_PER_B;        // group within batch
        const int q   = rem / QDIV;                  // candidate frame, 0..NF
        const int r   = rem * 4 - q * SHIFT;         // offset in frame q
        bv[k] = b; remv[k] = rem; qv[k] = q;
        const float* __restrict__ inb = in + b * (NF * FS);
        va[k] = {0.f, 0.f, 0.f, 0.f};
        vb[k] = {0.f, 0.f, 0.f, 0.f};
        if (valid[k]) {
            if (q < NF)                              // frame q, offset r
                va[k] = *(const f32x4*)(inb + q * FS + r);
            if (q >= 1)                              // frame q-1, offset r+SHIFT
                vb[k] = *(const f32x4*)(inb + (q - 1) * FS + r + SHIFT);
        }
    }

    // Phase 2: combine + store (full-line coalesced).
    #pragma unroll
    for (int k = 0; k < U; ++k) {
        if (!valid[k]) continue;
        const int q = qv[k];
        const float s = (q >= 1 && q < NF) ? 0.5f : 1.0f;
        const f32x4 o = (va[k] + vb[k]) * s;
        *(f32x4*)(out + bv[k] * SIG_LEN + remv[k] * 4) = o;
    }
}

extern "C" void kernel_launch(void* const* d_in, const int* in_sizes, int n_in,
                              void* d_out, int out_size, void* d_ws, size_t ws_size,
                              hipStream_t stream) {
    const float* in = (const float*)d_in[0];
    float* out = (float*)d_out;

    ola_gather_wu4<<<NBLOCKS, BLOCK, 0, stream>>>(in, out);
}